// Round 1
// baseline (244.068 us; speedup 1.0000x reference)
//
#include <hip/hip_runtime.h>
#include <math.h>

#define BLOCK 128
#define ROWS_PER_BLOCK 128
#define K 512
#define K4 128          // K/4
#define NQ 4
#define NL 6
#define NC 10

__global__ __launch_bounds__(BLOCK) void vqc_fused_kernel(
    const float* __restrict__ x,
    const float* __restrict__ W_pre,
    const float* __restrict__ b_pre,
    const float* __restrict__ q_weights,
    const float* __restrict__ W_post,
    const float* __restrict__ b_post,
    float* __restrict__ out)
{
    // LDS: W_pre 8KB + gates 768B + angles 2KB + small params  (~11 KB total)
    __shared__ float Ws[NQ * K];              // [w][k]
    __shared__ float gates[NL * NQ][8];       // g00r,g00i,g01r,g01i,g10r,g10i,g11r,g11i
    __shared__ float angles_s[ROWS_PER_BLOCK][NQ];
    __shared__ float Wpost_s[NC * NQ];
    __shared__ float bpost_s[NC];
    __shared__ float bpre_s[NQ];

    const int tid = threadIdx.x;

    // ---- stage W_pre (coalesced float4) ----
    {
        const float4* src = (const float4*)W_pre;
        float4* dst = (float4*)Ws;
        #pragma unroll
        for (int i = 0; i < (NQ * K4) / BLOCK; ++i)
            dst[tid + i * BLOCK] = src[tid + i * BLOCK];
    }
    // ---- precompute the 24 Rot gate matrices (batch-invariant) ----
    if (tid < NL * NQ) {
        const int l = tid >> 2, w = tid & 3;
        const float phi = q_weights[l * 12 + w * 3 + 0];
        const float th  = q_weights[l * 12 + w * 3 + 1];
        const float om  = q_weights[l * 12 + w * 3 + 2];
        const float c  = cosf(0.5f * th), s = sinf(0.5f * th);
        const float hp = 0.5f * (phi + om), hm = 0.5f * (phi - om);
        const float epr = cosf(hp), epi = -sinf(hp);   // exp(-i(phi+om)/2)
        const float emr = cosf(hm), emi = -sinf(hm);   // exp(-i(phi-om)/2)
        gates[tid][0] =  epr * c;  gates[tid][1] =  epi * c;   // g00 = ep*c
        gates[tid][2] = -emr * s;  gates[tid][3] =  emi * s;   // g01 = -conj(em)*s
        gates[tid][4] =  emr * s;  gates[tid][5] =  emi * s;   // g10 = em*s
        gates[tid][6] =  epr * c;  gates[tid][7] = -epi * c;   // g11 = conj(ep)*c
    }
    if (tid >= 64 && tid < 64 + NC * NQ) Wpost_s[tid - 64] = W_post[tid - 64];
    if (tid >= 104 && tid < 104 + NC)    bpost_s[tid - 104] = b_post[tid - 104];
    if (tid >= 114 && tid < 114 + NQ)    bpre_s[tid - 114]  = b_pre[tid - 114];
    __syncthreads();

    // ---- phase 1: pre-net GEMV, 4 lanes per row (coalesced 64B/group) ----
    const int j = tid & 3;          // k-slice lane within group
    const int g = tid >> 2;         // group 0..31
    const int rowBase = blockIdx.x * ROWS_PER_BLOCK;
    const float4* x4  = (const float4*)x;
    const float4* Ws4 = (const float4*)Ws;

    for (int s = 0; s < ROWS_PER_BLOCK / 32; ++s) {
        const int rl = s * 32 + g;                 // local row
        const int r  = rowBase + rl;               // global row
        const float4* xrow = x4 + (size_t)r * K4;
        float acc0 = 0.f, acc1 = 0.f, acc2 = 0.f, acc3 = 0.f;
        #pragma unroll 8
        for (int it = 0; it < 32; ++it) {
            const int f4 = it * 4 + j;
            const float4 xv = xrow[f4];
            const float4 w0 = Ws4[0 * K4 + f4];    // 16-way LDS broadcast
            const float4 w1 = Ws4[1 * K4 + f4];
            const float4 w2 = Ws4[2 * K4 + f4];
            const float4 w3 = Ws4[3 * K4 + f4];
            acc0 += xv.x * w0.x + xv.y * w0.y + xv.z * w0.z + xv.w * w0.w;
            acc1 += xv.x * w1.x + xv.y * w1.y + xv.z * w1.z + xv.w * w1.w;
            acc2 += xv.x * w2.x + xv.y * w2.y + xv.z * w2.z + xv.w * w2.w;
            acc3 += xv.x * w3.x + xv.y * w3.y + xv.z * w3.z + xv.w * w3.w;
        }
        // butterfly over the 4-lane group
        acc0 += __shfl_xor(acc0, 1); acc0 += __shfl_xor(acc0, 2);
        acc1 += __shfl_xor(acc1, 1); acc1 += __shfl_xor(acc1, 2);
        acc2 += __shfl_xor(acc2, 1); acc2 += __shfl_xor(acc2, 2);
        acc3 += __shfl_xor(acc3, 1); acc3 += __shfl_xor(acc3, 2);
        const float accj = (j == 0) ? acc0 : (j == 1) ? acc1 : (j == 2) ? acc2 : acc3;
        angles_s[rl][j] = tanhf(accj + bpre_s[j]) * 3.14159265358979323846f;
    }
    __syncthreads();

    // ---- phase 2: one thread per row, 16-amp state in registers ----
    {
        const int rl = tid;
        const int r  = rowBase + rl;
        const float a0 = angles_s[rl][0], a1 = angles_s[rl][1];
        const float a2 = angles_s[rl][2], a3 = angles_s[rl][3];
        float c0, s0, c1, s1, c2, s2, c3, s3;
        __sincosf(0.5f * a0, &s0, &c0);
        __sincosf(0.5f * a1, &s1, &c1);
        __sincosf(0.5f * a2, &s2, &c2);
        __sincosf(0.5f * a3, &s3, &c3);

        // |psi> = RY(a0)|0> ⊗ RY(a1)|0> ⊗ RY(a2)|0> ⊗ RY(a3)|0>   (real)
        float ar[16], ai[16];
        #pragma unroll
        for (int i = 0; i < 16; ++i) {
            ar[i] = ((i & 8) ? s0 : c0) * ((i & 4) ? s1 : c1)
                  * ((i & 2) ? s2 : c2) * ((i & 1) ? s3 : c3);
            ai[i] = 0.f;
        }

        #pragma unroll
        for (int l = 0; l < NL; ++l) {
            #pragma unroll
            for (int w = 0; w < NQ; ++w) {
                const float* G = gates[l * 4 + w];
                const float g00r = G[0], g00i = G[1], g01r = G[2], g01i = G[3];
                const float g10r = G[4], g10i = G[5], g11r = G[6], g11i = G[7];
                const int m = 8 >> w;
                #pragma unroll
                for (int i0 = 0; i0 < 16; ++i0) {
                    if (i0 & m) continue;
                    const int i1 = i0 | m;
                    const float A0r = ar[i0], A0i = ai[i0];
                    const float A1r = ar[i1], A1i = ai[i1];
                    ar[i0] = g00r * A0r - g00i * A0i + g01r * A1r - g01i * A1i;
                    ai[i0] = g00r * A0i + g00i * A0r + g01r * A1i + g01i * A1r;
                    ar[i1] = g10r * A0r - g10i * A0i + g11r * A1r - g11i * A1i;
                    ai[i1] = g10r * A0i + g10i * A0r + g11r * A1i + g11i * A1r;
                }
            }
            const int rr = l % 3 + 1;
            #pragma unroll
            for (int w = 0; w < NQ; ++w) {
                const int cm = 8 >> w;
                const int tm = 8 >> ((w + rr) & 3);
                #pragma unroll
                for (int i = 0; i < 16; ++i) {
                    if ((i & cm) && !(i & tm)) {
                        const int ii = i | tm;
                        float t;
                        t = ar[i]; ar[i] = ar[ii]; ar[ii] = t;
                        t = ai[i]; ai[i] = ai[ii]; ai[ii] = t;
                    }
                }
            }
        }

        // Z expectations per wire
        float e0 = 0.f, e1 = 0.f, e2 = 0.f, e3 = 0.f;
        #pragma unroll
        for (int i = 0; i < 16; ++i) {
            const float p = ar[i] * ar[i] + ai[i] * ai[i];
            e0 += (i & 8) ? -p : p;
            e1 += (i & 4) ? -p : p;
            e2 += (i & 2) ? -p : p;
            e3 += (i & 1) ? -p : p;
        }

        // post-net 4 -> 10
        float* orow = out + (size_t)r * NC;
        #pragma unroll
        for (int c = 0; c < NC; ++c) {
            orow[c] = bpost_s[c]
                    + Wpost_s[c * 4 + 0] * e0 + Wpost_s[c * 4 + 1] * e1
                    + Wpost_s[c * 4 + 2] * e2 + Wpost_s[c * 4 + 3] * e3;
        }
    }
}

extern "C" void kernel_launch(void* const* d_in, const int* in_sizes, int n_in,
                              void* d_out, int out_size, void* d_ws, size_t ws_size,
                              hipStream_t stream) {
    const float* x         = (const float*)d_in[0];
    const float* W_pre     = (const float*)d_in[1];
    const float* b_pre     = (const float*)d_in[2];
    const float* q_weights = (const float*)d_in[3];
    const float* W_post    = (const float*)d_in[4];
    const float* b_post    = (const float*)d_in[5];
    float* out = (float*)d_out;

    const int B = in_sizes[0] / K;   // 65536
    dim3 grid(B / ROWS_PER_BLOCK);   // 512 blocks
    vqc_fused_kernel<<<grid, BLOCK, 0, stream>>>(x, W_pre, b_pre, q_weights,
                                                 W_post, b_post, out);
}

// Round 2
// 214.929 us; speedup vs baseline: 1.1356x; 1.1356x over previous
//
#include <hip/hip_runtime.h>
#include <math.h>

#define BLOCK 256
#define WAVES_PER_BLOCK 4
#define ROWS_PER_WAVE 8
#define ROWS_PER_BLOCK 32   // WAVES_PER_BLOCK * ROWS_PER_WAVE
#define K 512
#define K4 128              // K/4
#define NQ 4
#define NL 6
#define NC 10

__global__ __launch_bounds__(BLOCK, 4) void vqc_fused_kernel(
    const float* __restrict__ x,
    const float* __restrict__ W_pre,
    const float* __restrict__ b_pre,
    const float* __restrict__ q_weights,
    const float* __restrict__ W_post,
    const float* __restrict__ b_post,
    float* __restrict__ out)
{
    __shared__ float gates[NL * NQ][8];            // 768 B
    __shared__ float angles_s[ROWS_PER_BLOCK][NQ]; // 512 B
    __shared__ float Wpost_s[NC * NQ];
    __shared__ float bpost_s[NC];
    __shared__ float bpre_s[NQ];

    const int tid  = threadIdx.x;
    const int wave = tid >> 6;
    const int lane = tid & 63;

    // ---- precompute the 24 Rot gate matrices (batch-invariant) ----
    if (tid < NL * NQ) {
        const int l = tid >> 2, w = tid & 3;
        const float phi = q_weights[l * 12 + w * 3 + 0];
        const float th  = q_weights[l * 12 + w * 3 + 1];
        const float om  = q_weights[l * 12 + w * 3 + 2];
        const float c  = cosf(0.5f * th), s = sinf(0.5f * th);
        const float hp = 0.5f * (phi + om), hm = 0.5f * (phi - om);
        const float epr = cosf(hp), epi = -sinf(hp);   // exp(-i(phi+om)/2)
        const float emr = cosf(hm), emi = -sinf(hm);   // exp(-i(phi-om)/2)
        gates[tid][0] =  epr * c;  gates[tid][1] =  epi * c;   // g00 = ep*c
        gates[tid][2] = -emr * s;  gates[tid][3] =  emi * s;   // g01 = -conj(em)*s
        gates[tid][4] =  emr * s;  gates[tid][5] =  emi * s;   // g10 = em*s
        gates[tid][6] =  epr * c;  gates[tid][7] = -epi * c;   // g11 = conj(ep)*c
    }
    if (tid >= 64 && tid < 64 + NC * NQ) Wpost_s[tid - 64] = W_post[tid - 64];
    if (tid >= 104 && tid < 104 + NC)    bpost_s[tid - 104] = b_post[tid - 104];
    if (tid >= 114 && tid < 114 + NQ)    bpre_s[tid - 114]  = b_pre[tid - 114];
    __syncthreads();

    // ---- phase 1: one wave per row, W_pre in registers ----
    // lane owns k-slices {lane, 64+lane} (float4 units); W regs live across rows
    const float4* x4 = (const float4*)x;
    const float4* W4 = (const float4*)W_pre;
    const float4 w0a = W4[0 * K4 + lane], w0b = W4[0 * K4 + 64 + lane];
    const float4 w1a = W4[1 * K4 + lane], w1b = W4[1 * K4 + 64 + lane];
    const float4 w2a = W4[2 * K4 + lane], w2b = W4[2 * K4 + 64 + lane];
    const float4 w3a = W4[3 * K4 + lane], w3b = W4[3 * K4 + 64 + lane];

    const int rowBase = blockIdx.x * ROWS_PER_BLOCK + wave * ROWS_PER_WAVE;

    #pragma unroll 4
    for (int rr = 0; rr < ROWS_PER_WAVE; ++rr) {
        const int r = rowBase + rr;
        const float4* xrow = x4 + (size_t)r * K4;
        const float4 xa = xrow[lane];
        const float4 xb = xrow[64 + lane];
        float acc0 = xa.x * w0a.x + xa.y * w0a.y + xa.z * w0a.z + xa.w * w0a.w
                   + xb.x * w0b.x + xb.y * w0b.y + xb.z * w0b.z + xb.w * w0b.w;
        float acc1 = xa.x * w1a.x + xa.y * w1a.y + xa.z * w1a.z + xa.w * w1a.w
                   + xb.x * w1b.x + xb.y * w1b.y + xb.z * w1b.z + xb.w * w1b.w;
        float acc2 = xa.x * w2a.x + xa.y * w2a.y + xa.z * w2a.z + xa.w * w2a.w
                   + xb.x * w2b.x + xb.y * w2b.y + xb.z * w2b.z + xb.w * w2b.w;
        float acc3 = xa.x * w3a.x + xa.y * w3a.y + xa.z * w3a.z + xa.w * w3a.w
                   + xb.x * w3b.x + xb.y * w3b.y + xb.z * w3b.z + xb.w * w3b.w;
        // full-wave butterfly reduction (all 64 lanes end with totals)
        #pragma unroll
        for (int m = 1; m < 64; m <<= 1) {
            acc0 += __shfl_xor(acc0, m);
            acc1 += __shfl_xor(acc1, m);
            acc2 += __shfl_xor(acc2, m);
            acc3 += __shfl_xor(acc3, m);
        }
        if (lane < NQ) {
            const float accj = (lane == 0) ? acc0 : (lane == 1) ? acc1
                             : (lane == 2) ? acc2 : acc3;
            angles_s[wave * ROWS_PER_WAVE + rr][lane] =
                tanhf(accj + bpre_s[lane]) * 3.14159265358979323846f;
        }
    }
    __syncthreads();

    // ---- phase 2: one thread per row, 16-amp state in registers ----
    if (tid < ROWS_PER_BLOCK) {
        const int rl = tid;
        const int r  = blockIdx.x * ROWS_PER_BLOCK + rl;
        const float a0 = angles_s[rl][0], a1 = angles_s[rl][1];
        const float a2 = angles_s[rl][2], a3 = angles_s[rl][3];
        float c0, s0, c1, s1, c2, s2, c3, s3;
        __sincosf(0.5f * a0, &s0, &c0);
        __sincosf(0.5f * a1, &s1, &c1);
        __sincosf(0.5f * a2, &s2, &c2);
        __sincosf(0.5f * a3, &s3, &c3);

        float ar[16], ai[16];
        #pragma unroll
        for (int i = 0; i < 16; ++i) {
            ar[i] = ((i & 8) ? s0 : c0) * ((i & 4) ? s1 : c1)
                  * ((i & 2) ? s2 : c2) * ((i & 1) ? s3 : c3);
            ai[i] = 0.f;
        }

        #pragma unroll
        for (int l = 0; l < NL; ++l) {
            #pragma unroll
            for (int w = 0; w < NQ; ++w) {
                const float* G = gates[l * 4 + w];
                const float g00r = G[0], g00i = G[1], g01r = G[2], g01i = G[3];
                const float g10r = G[4], g10i = G[5], g11r = G[6], g11i = G[7];
                const int m = 8 >> w;
                #pragma unroll
                for (int i0 = 0; i0 < 16; ++i0) {
                    if (i0 & m) continue;
                    const int i1 = i0 | m;
                    const float A0r = ar[i0], A0i = ai[i0];
                    const float A1r = ar[i1], A1i = ai[i1];
                    ar[i0] = g00r * A0r - g00i * A0i + g01r * A1r - g01i * A1i;
                    ai[i0] = g00r * A0i + g00i * A0r + g01r * A1i + g01i * A1r;
                    ar[i1] = g10r * A0r - g10i * A0i + g11r * A1r - g11i * A1i;
                    ai[i1] = g10r * A0i + g10i * A0r + g11r * A1i + g11i * A1r;
                }
            }
            const int rshift = l % 3 + 1;
            #pragma unroll
            for (int w = 0; w < NQ; ++w) {
                const int cm = 8 >> w;
                const int tm = 8 >> ((w + rshift) & 3);
                #pragma unroll
                for (int i = 0; i < 16; ++i) {
                    if ((i & cm) && !(i & tm)) {
                        const int ii = i | tm;
                        float t;
                        t = ar[i]; ar[i] = ar[ii]; ar[ii] = t;
                        t = ai[i]; ai[i] = ai[ii]; ai[ii] = t;
                    }
                }
            }
        }

        float e0 = 0.f, e1 = 0.f, e2 = 0.f, e3 = 0.f;
        #pragma unroll
        for (int i = 0; i < 16; ++i) {
            const float p = ar[i] * ar[i] + ai[i] * ai[i];
            e0 += (i & 8) ? -p : p;
            e1 += (i & 4) ? -p : p;
            e2 += (i & 2) ? -p : p;
            e3 += (i & 1) ? -p : p;
        }

        float* orow = out + (size_t)r * NC;
        #pragma unroll
        for (int c = 0; c < NC; ++c) {
            orow[c] = bpost_s[c]
                    + Wpost_s[c * 4 + 0] * e0 + Wpost_s[c * 4 + 1] * e1
                    + Wpost_s[c * 4 + 2] * e2 + Wpost_s[c * 4 + 3] * e3;
        }
    }
}

extern "C" void kernel_launch(void* const* d_in, const int* in_sizes, int n_in,
                              void* d_out, int out_size, void* d_ws, size_t ws_size,
                              hipStream_t stream) {
    const float* x         = (const float*)d_in[0];
    const float* W_pre     = (const float*)d_in[1];
    const float* b_pre     = (const float*)d_in[2];
    const float* q_weights = (const float*)d_in[3];
    const float* W_post    = (const float*)d_in[4];
    const float* b_post    = (const float*)d_in[5];
    float* out = (float*)d_out;

    const int B = in_sizes[0] / K;          // 65536
    dim3 grid(B / ROWS_PER_BLOCK);          // 2048 blocks
    vqc_fused_kernel<<<grid, BLOCK, 0, stream>>>(x, W_pre, b_pre, q_weights,
                                                 W_post, b_post, out);
}

// Round 3
// 210.995 us; speedup vs baseline: 1.1568x; 1.0186x over previous
//
#include <hip/hip_runtime.h>
#include <math.h>

#define K 512
#define K4 128              // K/4
#define NQ 4
#define NL 6
#define NC 10

// ================= Kernel A: pre-net GEMV + tanh -> angles =================
// one wave per row, W_pre in registers, folded 7-shuffle reduction,
// next-row prefetch overlaps the fold chain.
#define A_BLOCK 256
#define A_ROWS_PER_WAVE 8
#define A_ROWS_PER_BLOCK 32  // 4 waves * 8 rows

__global__ __launch_bounds__(A_BLOCK, 4) void prenet_kernel(
    const float* __restrict__ x,
    const float* __restrict__ W_pre,
    const float* __restrict__ b_pre,
    float* __restrict__ angles)
{
    const int tid  = threadIdx.x;
    const int wave = tid >> 6;
    const int lane = tid & 63;

    const float4* x4 = (const float4*)x;
    const float4* W4 = (const float4*)W_pre;
    // lane owns k-slices {lane, 64+lane}; W regs live across all rows
    const float4 w0a = W4[0 * K4 + lane], w0b = W4[0 * K4 + 64 + lane];
    const float4 w1a = W4[1 * K4 + lane], w1b = W4[1 * K4 + 64 + lane];
    const float4 w2a = W4[2 * K4 + lane], w2b = W4[2 * K4 + 64 + lane];
    const float4 w3a = W4[3 * K4 + lane], w3b = W4[3 * K4 + 64 + lane];
    const float bp = (lane < NQ) ? b_pre[lane] : 0.f;

    const int rowBase = blockIdx.x * A_ROWS_PER_BLOCK + wave * A_ROWS_PER_WAVE;
    const float4* xrow0 = x4 + (size_t)rowBase * K4;
    float4 xa = xrow0[lane];
    float4 xb = xrow0[64 + lane];

    #pragma unroll
    for (int rr = 0; rr < A_ROWS_PER_WAVE; ++rr) {
        // prefetch next row while this row's FMA + fold chain runs
        float4 na = xa, nb = xb;
        if (rr + 1 < A_ROWS_PER_WAVE) {
            const float4* nx = x4 + (size_t)(rowBase + rr + 1) * K4;
            na = nx[lane];
            nb = nx[64 + lane];
        }

        float acc0 = xa.x * w0a.x + xa.y * w0a.y + xa.z * w0a.z + xa.w * w0a.w
                   + xb.x * w0b.x + xb.y * w0b.y + xb.z * w0b.z + xb.w * w0b.w;
        float acc1 = xa.x * w1a.x + xa.y * w1a.y + xa.z * w1a.z + xa.w * w1a.w
                   + xb.x * w1b.x + xb.y * w1b.y + xb.z * w1b.z + xb.w * w1b.w;
        float acc2 = xa.x * w2a.x + xa.y * w2a.y + xa.z * w2a.z + xa.w * w2a.w
                   + xb.x * w2b.x + xb.y * w2b.y + xb.z * w2b.z + xb.w * w2b.w;
        float acc3 = xa.x * w3a.x + xa.y * w3a.y + xa.z * w3a.z + xa.w * w3a.w
                   + xb.x * w3b.x + xb.y * w3b.y + xb.z * w3b.z + xb.w * w3b.w;

        // folded reduction: 7 shuffles total (vs 24 for 4x full butterfly)
        // stage 1 (xor 1): fold 4 accs -> 2
        const bool b0 = (lane & 1);
        float pA = b0 ? acc1 : acc0;
        float qA = b0 ? acc0 : acc1;
        pA += __shfl_xor(qA, 1);
        float pB = b0 ? acc3 : acc2;
        float qB = b0 ? acc2 : acc3;
        pB += __shfl_xor(qB, 1);
        // stage 2 (xor 2): fold 2 -> 1; now value index = lane & 3
        const bool b1 = (lane & 2);
        float p = b1 ? pB : pA;
        float q = b1 ? pA : pB;
        p += __shfl_xor(q, 2);
        // stages 3-6: plain butterfly over remaining groups
        p += __shfl_xor(p, 4);
        p += __shfl_xor(p, 8);
        p += __shfl_xor(p, 16);
        p += __shfl_xor(p, 32);
        // lane j (j<4) now holds the full dot product for wire j

        if (lane < NQ) {
            const float z = p + bp;
            // tanh(z) = 1 - 2/(exp(2z)+1), exp via hardware v_exp_f32
            const float e = __expf(2.f * z);
            const float th = 1.f - 2.f / (e + 1.f);
            angles[(size_t)(rowBase + rr) * NQ + lane] =
                th * 3.14159265358979323846f;
        }
        xa = na; xb = nb;
    }
}

// ============ Kernel B: quantum sim + post-net, one thread per row ============
#define B_BLOCK 256

__global__ __launch_bounds__(B_BLOCK, 4) void vqc_kernel(
    const float* __restrict__ angles,
    const float* __restrict__ q_weights,
    const float* __restrict__ W_post,
    const float* __restrict__ b_post,
    float* __restrict__ out)
{
    __shared__ float gates[NL * NQ][8];
    __shared__ float Wpost_s[NC * NQ];
    __shared__ float bpost_s[NC];

    const int tid = threadIdx.x;

    // precompute the 24 Rot gate matrices (batch-invariant)
    if (tid < NL * NQ) {
        const int l = tid >> 2, w = tid & 3;
        const float phi = q_weights[l * 12 + w * 3 + 0];
        const float th  = q_weights[l * 12 + w * 3 + 1];
        const float om  = q_weights[l * 12 + w * 3 + 2];
        const float c  = cosf(0.5f * th), s = sinf(0.5f * th);
        const float hp = 0.5f * (phi + om), hm = 0.5f * (phi - om);
        const float epr = cosf(hp), epi = -sinf(hp);   // exp(-i(phi+om)/2)
        const float emr = cosf(hm), emi = -sinf(hm);   // exp(-i(phi-om)/2)
        gates[tid][0] =  epr * c;  gates[tid][1] =  epi * c;   // g00 = ep*c
        gates[tid][2] = -emr * s;  gates[tid][3] =  emi * s;   // g01 = -conj(em)*s
        gates[tid][4] =  emr * s;  gates[tid][5] =  emi * s;   // g10 = em*s
        gates[tid][6] =  epr * c;  gates[tid][7] = -epi * c;   // g11 = conj(ep)*c
    }
    if (tid >= 64 && tid < 64 + NC * NQ) Wpost_s[tid - 64] = W_post[tid - 64];
    if (tid >= 104 && tid < 104 + NC)    bpost_s[tid - 104] = b_post[tid - 104];
    __syncthreads();

    const int r = blockIdx.x * B_BLOCK + tid;
    const float4 a = ((const float4*)angles)[r];   // coalesced 16B/lane

    float c0, s0, c1, s1, c2, s2, c3, s3;
    __sincosf(0.5f * a.x, &s0, &c0);
    __sincosf(0.5f * a.y, &s1, &c1);
    __sincosf(0.5f * a.z, &s2, &c2);
    __sincosf(0.5f * a.w, &s3, &c3);

    // |psi> = RY(a0)|0> x RY(a1)|0> x RY(a2)|0> x RY(a3)|0>  (real)
    float ar[16], ai[16];
    #pragma unroll
    for (int i = 0; i < 16; ++i) {
        ar[i] = ((i & 8) ? s0 : c0) * ((i & 4) ? s1 : c1)
              * ((i & 2) ? s2 : c2) * ((i & 1) ? s3 : c3);
        ai[i] = 0.f;
    }

    #pragma unroll
    for (int l = 0; l < NL; ++l) {
        #pragma unroll
        for (int w = 0; w < NQ; ++w) {
            const float* G = gates[l * 4 + w];     // LDS broadcast, conflict-free
            const float g00r = G[0], g00i = G[1], g01r = G[2], g01i = G[3];
            const float g10r = G[4], g10i = G[5], g11r = G[6], g11i = G[7];
            const int m = 8 >> w;
            #pragma unroll
            for (int i0 = 0; i0 < 16; ++i0) {
                if (i0 & m) continue;
                const int i1 = i0 | m;
                const float A0r = ar[i0], A0i = ai[i0];
                const float A1r = ar[i1], A1i = ai[i1];
                ar[i0] = g00r * A0r - g00i * A0i + g01r * A1r - g01i * A1i;
                ai[i0] = g00r * A0i + g00i * A0r + g01r * A1i + g01i * A1r;
                ar[i1] = g10r * A0r - g10i * A0i + g11r * A1r - g11i * A1i;
                ai[i1] = g10r * A0i + g10i * A0r + g11r * A1i + g11i * A1r;
            }
        }
        const int rshift = l % 3 + 1;
        // CNOT ring: pure compile-time register permutation
        #pragma unroll
        for (int w = 0; w < NQ; ++w) {
            const int cm = 8 >> w;
            const int tm = 8 >> ((w + rshift) & 3);
            #pragma unroll
            for (int i = 0; i < 16; ++i) {
                if ((i & cm) && !(i & tm)) {
                    const int ii = i | tm;
                    float t;
                    t = ar[i]; ar[i] = ar[ii]; ar[ii] = t;
                    t = ai[i]; ai[i] = ai[ii]; ai[ii] = t;
                }
            }
        }
    }

    // Z expectations per wire
    float e0 = 0.f, e1 = 0.f, e2 = 0.f, e3 = 0.f;
    #pragma unroll
    for (int i = 0; i < 16; ++i) {
        const float pr = ar[i] * ar[i] + ai[i] * ai[i];
        e0 += (i & 8) ? -pr : pr;
        e1 += (i & 4) ? -pr : pr;
        e2 += (i & 2) ? -pr : pr;
        e3 += (i & 1) ? -pr : pr;
    }

    // post-net 4 -> 10, stored as 5 aligned float2 (row byte offset 40r, 8B-aligned)
    float o[NC];
    #pragma unroll
    for (int c = 0; c < NC; ++c) {
        o[c] = bpost_s[c]
             + Wpost_s[c * 4 + 0] * e0 + Wpost_s[c * 4 + 1] * e1
             + Wpost_s[c * 4 + 2] * e2 + Wpost_s[c * 4 + 3] * e3;
    }
    float2* orow2 = (float2*)(out + (size_t)r * NC);
    #pragma unroll
    for (int c = 0; c < 5; ++c)
        orow2[c] = make_float2(o[2 * c], o[2 * c + 1]);
}

extern "C" void kernel_launch(void* const* d_in, const int* in_sizes, int n_in,
                              void* d_out, int out_size, void* d_ws, size_t ws_size,
                              hipStream_t stream) {
    const float* x         = (const float*)d_in[0];
    const float* W_pre     = (const float*)d_in[1];
    const float* b_pre     = (const float*)d_in[2];
    const float* q_weights = (const float*)d_in[3];
    const float* W_post    = (const float*)d_in[4];
    const float* b_post    = (const float*)d_in[5];
    float* out    = (float*)d_out;
    float* angles = (float*)d_ws;               // 65536*4 floats = 1 MB

    const int B = in_sizes[0] / K;              // 65536
    dim3 gridA(B / A_ROWS_PER_BLOCK);           // 2048 blocks
    prenet_kernel<<<gridA, A_BLOCK, 0, stream>>>(x, W_pre, b_pre, angles);
    dim3 gridB(B / B_BLOCK);                    // 256 blocks
    vqc_kernel<<<gridB, B_BLOCK, 0, stream>>>(angles, q_weights, W_post, b_post, out);
}

// Round 4
// 208.572 us; speedup vs baseline: 1.1702x; 1.0116x over previous
//
#include <hip/hip_runtime.h>
#include <math.h>

#define K 512
#define K4 128              // K/4
#define NQ 4
#define NL 6
#define NC 10

// DPP quad_perm cross-lane xor (pure VALU, no DS pipe)
__device__ __forceinline__ float dpp_xor1(float v) {
    return __int_as_float(__builtin_amdgcn_mov_dpp(__float_as_int(v), 0xB1, 0xF, 0xF, true));
}
__device__ __forceinline__ float dpp_xor2(float v) {
    return __int_as_float(__builtin_amdgcn_mov_dpp(__float_as_int(v), 0x4E, 0xF, 0xF, true));
}

// ================= Kernel A: pre-net GEMV + tanh -> angles =================
// wave-per-row, W_pre in registers, DPP-only per-row fold (no DS chain),
// batched LDS tail reduction. grid=1024 -> exactly 4 blocks/CU, single round.
#define A_BLOCK 256
#define A_WAVES 4
#define A_ROWS_PER_WAVE 16
#define A_ROWS_PER_BLOCK 64   // A_WAVES * A_ROWS_PER_WAVE
#define PART_STRIDE 68        // 64 partials + pad, multiple of 4 for b128 align

__global__ __launch_bounds__(A_BLOCK, 4) void prenet_kernel(
    const float* __restrict__ x,
    const float* __restrict__ W_pre,
    const float* __restrict__ b_pre,
    float* __restrict__ angles)
{
    __shared__ float part[A_ROWS_PER_BLOCK * PART_STRIDE];  // 17.4 KB

    const int tid  = threadIdx.x;
    const int wave = tid >> 6;
    const int lane = tid & 63;

    const float4* x4 = (const float4*)x;
    const float4* W4 = (const float4*)W_pre;
    // lane owns k-slices {lane, 64+lane} (float4 units); W regs live across rows
    const float4 w0a = W4[0 * K4 + lane], w0b = W4[0 * K4 + 64 + lane];
    const float4 w1a = W4[1 * K4 + lane], w1b = W4[1 * K4 + 64 + lane];
    const float4 w2a = W4[2 * K4 + lane], w2b = W4[2 * K4 + 64 + lane];
    const float4 w3a = W4[3 * K4 + lane], w3b = W4[3 * K4 + 64 + lane];

    const int rowBase = blockIdx.x * A_ROWS_PER_BLOCK + wave * A_ROWS_PER_WAVE;

    // LDS destination for this lane's per-row partial:
    // lane holds (wire = lane&3, seg = lane>>2) after the DPP fold
    const int partOff = (lane & 3) * 16 + (lane >> 2);

    const float4* xrow0 = x4 + (size_t)rowBase * K4;
    float4 xa = xrow0[lane];
    float4 xb = xrow0[64 + lane];

    #pragma unroll
    for (int rr = 0; rr < A_ROWS_PER_WAVE; ++rr) {
        float4 na = xa, nb = xb;
        if (rr + 1 < A_ROWS_PER_WAVE) {
            const float4* nx = x4 + (size_t)(rowBase + rr + 1) * K4;
            na = nx[lane];
            nb = nx[64 + lane];
        }

        float acc0 = xa.x * w0a.x + xa.y * w0a.y + xa.z * w0a.z + xa.w * w0a.w
                   + xb.x * w0b.x + xb.y * w0b.y + xb.z * w0b.z + xb.w * w0b.w;
        float acc1 = xa.x * w1a.x + xa.y * w1a.y + xa.z * w1a.z + xa.w * w1a.w
                   + xb.x * w1b.x + xb.y * w1b.y + xb.z * w1b.z + xb.w * w1b.w;
        float acc2 = xa.x * w2a.x + xa.y * w2a.y + xa.z * w2a.z + xa.w * w2a.w
                   + xb.x * w2b.x + xb.y * w2b.y + xb.z * w2b.z + xb.w * w2b.w;
        float acc3 = xa.x * w3a.x + xa.y * w3a.y + xa.z * w3a.z + xa.w * w3a.w
                   + xb.x * w3b.x + xb.y * w3b.y + xb.z * w3b.z + xb.w * w3b.w;

        // fold 4 accs -> 1 per lane using only quad-local DPP (VALU, ~2cyc each)
        const bool b0 = (lane & 1);
        float pA = b0 ? acc1 : acc0;
        float qA = b0 ? acc0 : acc1;
        pA += dpp_xor1(qA);
        float pB = b0 ? acc3 : acc2;
        float qB = b0 ? acc2 : acc3;
        pB += dpp_xor1(qB);
        const bool b1 = (lane & 2);
        float p = b1 ? pB : pA;
        float q = b1 ? pA : pB;
        p += dpp_xor2(q);
        // lane now holds partial dot for wire (lane&3) over segment (lane>>2)

        part[(wave * A_ROWS_PER_WAVE + rr) * PART_STRIDE + partOff] = p;

        xa = na; xb = nb;
    }
    __syncthreads();

    // ---- tail: one thread per (row, wire), sum 16 segment partials ----
    {
        const int row  = tid >> 2;          // 0..63
        const int wire = tid & 3;
        const float4* seg4 = (const float4*)&part[row * PART_STRIDE + wire * 16];
        const float4 s0 = seg4[0], s1 = seg4[1], s2 = seg4[2], s3 = seg4[3];
        const float s = ((s0.x + s0.y) + (s0.z + s0.w))
                      + ((s1.x + s1.y) + (s1.z + s1.w))
                      + ((s2.x + s2.y) + (s2.z + s2.w))
                      + ((s3.x + s3.y) + (s3.z + s3.w));
        const float z = s + b_pre[wire];
        // tanh(z) = 1 - 2/(exp(2z)+1), exp via hardware v_exp_f32
        const float e = __expf(2.f * z);
        const float th = 1.f - 2.f / (e + 1.f);
        // tid-contiguous store: angles[blockBase*4 + tid]
        angles[(size_t)blockIdx.x * A_ROWS_PER_BLOCK * NQ + tid] =
            th * 3.14159265358979323846f;
    }
}

// ============ Kernel B: quantum sim + post-net, one thread per row ============
#define B_BLOCK 256

__global__ __launch_bounds__(B_BLOCK, 4) void vqc_kernel(
    const float* __restrict__ angles,
    const float* __restrict__ q_weights,
    const float* __restrict__ W_post,
    const float* __restrict__ b_post,
    float* __restrict__ out)
{
    __shared__ float gates[NL * NQ][8];
    __shared__ float Wpost_s[NC * NQ];
    __shared__ float bpost_s[NC];

    const int tid = threadIdx.x;

    // precompute the 24 Rot gate matrices (batch-invariant)
    if (tid < NL * NQ) {
        const int l = tid >> 2, w = tid & 3;
        const float phi = q_weights[l * 12 + w * 3 + 0];
        const float th  = q_weights[l * 12 + w * 3 + 1];
        const float om  = q_weights[l * 12 + w * 3 + 2];
        const float c  = cosf(0.5f * th), s = sinf(0.5f * th);
        const float hp = 0.5f * (phi + om), hm = 0.5f * (phi - om);
        const float epr = cosf(hp), epi = -sinf(hp);   // exp(-i(phi+om)/2)
        const float emr = cosf(hm), emi = -sinf(hm);   // exp(-i(phi-om)/2)
        gates[tid][0] =  epr * c;  gates[tid][1] =  epi * c;   // g00 = ep*c
        gates[tid][2] = -emr * s;  gates[tid][3] =  emi * s;   // g01 = -conj(em)*s
        gates[tid][4] =  emr * s;  gates[tid][5] =  emi * s;   // g10 = em*s
        gates[tid][6] =  epr * c;  gates[tid][7] = -epi * c;   // g11 = conj(ep)*c
    }
    if (tid >= 64 && tid < 64 + NC * NQ) Wpost_s[tid - 64] = W_post[tid - 64];
    if (tid >= 104 && tid < 104 + NC)    bpost_s[tid - 104] = b_post[tid - 104];
    __syncthreads();

    const int r = blockIdx.x * B_BLOCK + tid;
    const float4 a = ((const float4*)angles)[r];   // coalesced 16B/lane

    float c0, s0, c1, s1, c2, s2, c3, s3;
    __sincosf(0.5f * a.x, &s0, &c0);
    __sincosf(0.5f * a.y, &s1, &c1);
    __sincosf(0.5f * a.z, &s2, &c2);
    __sincosf(0.5f * a.w, &s3, &c3);

    // |psi> = RY(a0)|0> x RY(a1)|0> x RY(a2)|0> x RY(a3)|0>  (real)
    float ar[16], ai[16];
    #pragma unroll
    for (int i = 0; i < 16; ++i) {
        ar[i] = ((i & 8) ? s0 : c0) * ((i & 4) ? s1 : c1)
              * ((i & 2) ? s2 : c2) * ((i & 1) ? s3 : c3);
        ai[i] = 0.f;
    }

    #pragma unroll
    for (int l = 0; l < NL; ++l) {
        #pragma unroll
        for (int w = 0; w < NQ; ++w) {
            const float* G = gates[l * 4 + w];     // LDS broadcast, conflict-free
            const float g00r = G[0], g00i = G[1], g01r = G[2], g01i = G[3];
            const float g10r = G[4], g10i = G[5], g11r = G[6], g11i = G[7];
            const int m = 8 >> w;
            #pragma unroll
            for (int i0 = 0; i0 < 16; ++i0) {
                if (i0 & m) continue;
                const int i1 = i0 | m;
                const float A0r = ar[i0], A0i = ai[i0];
                const float A1r = ar[i1], A1i = ai[i1];
                ar[i0] = g00r * A0r - g00i * A0i + g01r * A1r - g01i * A1i;
                ai[i0] = g00r * A0i + g00i * A0r + g01r * A1i + g01i * A1r;
                ar[i1] = g10r * A0r - g10i * A0i + g11r * A1r - g11i * A1i;
                ai[i1] = g10r * A0i + g10i * A0r + g11r * A1i + g11i * A1r;
            }
        }
        const int rshift = l % 3 + 1;
        // CNOT ring: pure compile-time register permutation
        #pragma unroll
        for (int w = 0; w < NQ; ++w) {
            const int cm = 8 >> w;
            const int tm = 8 >> ((w + rshift) & 3);
            #pragma unroll
            for (int i = 0; i < 16; ++i) {
                if ((i & cm) && !(i & tm)) {
                    const int ii = i | tm;
                    float t;
                    t = ar[i]; ar[i] = ar[ii]; ar[ii] = t;
                    t = ai[i]; ai[i] = ai[ii]; ai[ii] = t;
                }
            }
        }
    }

    // Z expectations per wire
    float e0 = 0.f, e1 = 0.f, e2 = 0.f, e3 = 0.f;
    #pragma unroll
    for (int i = 0; i < 16; ++i) {
        const float pr = ar[i] * ar[i] + ai[i] * ai[i];
        e0 += (i & 8) ? -pr : pr;
        e1 += (i & 4) ? -pr : pr;
        e2 += (i & 2) ? -pr : pr;
        e3 += (i & 1) ? -pr : pr;
    }

    // post-net 4 -> 10, stored as 5 aligned float2 (row byte offset 40r, 8B-aligned)
    float o[NC];
    #pragma unroll
    for (int c = 0; c < NC; ++c) {
        o[c] = bpost_s[c]
             + Wpost_s[c * 4 + 0] * e0 + Wpost_s[c * 4 + 1] * e1
             + Wpost_s[c * 4 + 2] * e2 + Wpost_s[c * 4 + 3] * e3;
    }
    float2* orow2 = (float2*)(out + (size_t)r * NC);
    #pragma unroll
    for (int c = 0; c < 5; ++c)
        orow2[c] = make_float2(o[2 * c], o[2 * c + 1]);
}

extern "C" void kernel_launch(void* const* d_in, const int* in_sizes, int n_in,
                              void* d_out, int out_size, void* d_ws, size_t ws_size,
                              hipStream_t stream) {
    const float* x         = (const float*)d_in[0];
    const float* W_pre     = (const float*)d_in[1];
    const float* b_pre     = (const float*)d_in[2];
    const float* q_weights = (const float*)d_in[3];
    const float* W_post    = (const float*)d_in[4];
    const float* b_post    = (const float*)d_in[5];
    float* out    = (float*)d_out;
    float* angles = (float*)d_ws;               // 65536*4 floats = 1 MB

    const int B = in_sizes[0] / K;              // 65536
    dim3 gridA(B / A_ROWS_PER_BLOCK);           // 1024 blocks -> 4/CU, 1 round
    prenet_kernel<<<gridA, A_BLOCK, 0, stream>>>(x, W_pre, b_pre, angles);
    dim3 gridB(B / B_BLOCK);                    // 256 blocks
    vqc_kernel<<<gridB, B_BLOCK, 0, stream>>>(angles, q_weights, W_post, b_post, out);
}

// Round 5
// 207.992 us; speedup vs baseline: 1.1734x; 1.0028x over previous
//
#include <hip/hip_runtime.h>
#include <math.h>

#define K 512
#define K4 128              // K/4
#define NQ 4
#define NL 6
#define NC 10

// DPP quad_perm cross-lane xor (pure VALU, no DS pipe)
__device__ __forceinline__ float dpp_xor1(float v) {
    return __int_as_float(__builtin_amdgcn_mov_dpp(__float_as_int(v), 0xB1, 0xF, 0xF, true));
}
__device__ __forceinline__ float dpp_xor2(float v) {
    return __int_as_float(__builtin_amdgcn_mov_dpp(__float_as_int(v), 0x4E, 0xF, 0xF, true));
}

// ================= Kernel A: pre-net GEMV + tanh -> angles =================
// wave-per-row, W_pre in registers, explicit depth-2 row-pair pipeline with
// ping-pong buffers (bounded liveness ~90 VGPRs: no spill, 4KB/wave in flight).
#define A_BLOCK 256
#define A_WAVES 4
#define A_ROWS_PER_WAVE 16
#define A_ROWS_PER_BLOCK 64   // A_WAVES * A_ROWS_PER_WAVE
#define A_PAIRS 8             // 16 rows as 8 pairs
#define PART_STRIDE 68        // 64 partials + pad, multiple of 4 for b128 align

__global__ __launch_bounds__(A_BLOCK, 4) void prenet_kernel(
    const float* __restrict__ x,
    const float* __restrict__ W_pre,
    const float* __restrict__ b_pre,
    float* __restrict__ angles)
{
    __shared__ float part[A_ROWS_PER_BLOCK * PART_STRIDE];  // 17.4 KB

    const int tid  = threadIdx.x;
    const int wave = tid >> 6;
    const int lane = tid & 63;

    const float4* x4 = (const float4*)x;
    const float4* W4 = (const float4*)W_pre;
    // lane owns k-slices {lane, 64+lane} (float4 units); W regs live across rows
    const float4 w0a = W4[0 * K4 + lane], w0b = W4[0 * K4 + 64 + lane];
    const float4 w1a = W4[1 * K4 + lane], w1b = W4[1 * K4 + 64 + lane];
    const float4 w2a = W4[2 * K4 + lane], w2b = W4[2 * K4 + 64 + lane];
    const float4 w3a = W4[3 * K4 + lane], w3b = W4[3 * K4 + 64 + lane];

    const int rowBase = blockIdx.x * A_ROWS_PER_BLOCK + wave * A_ROWS_PER_WAVE;

    // LDS slot for this lane's per-row partial: (wire = lane&3, seg = lane>>2)
    const int partOff = (lane & 3) * 16 + (lane >> 2);

    // ping-pong row-pair buffers; all indices compile-time after unroll
    float4 bufa[2][2], bufb[2][2];   // [parity][row-in-pair]
    {
        const float4* r0 = x4 + (size_t)(rowBase + 0) * K4;
        const float4* r1 = x4 + (size_t)(rowBase + 1) * K4;
        bufa[0][0] = r0[lane]; bufb[0][0] = r0[64 + lane];
        bufa[0][1] = r1[lane]; bufb[0][1] = r1[64 + lane];
    }

    #pragma unroll
    for (int p = 0; p < A_PAIRS; ++p) {
        const int cp = p & 1, np = cp ^ 1;
        if (p + 1 < A_PAIRS) {      // prefetch next pair (4KB/wave in flight)
            const float4* r0 = x4 + (size_t)(rowBase + 2 * p + 2) * K4;
            const float4* r1 = x4 + (size_t)(rowBase + 2 * p + 3) * K4;
            bufa[np][0] = r0[lane]; bufb[np][0] = r0[64 + lane];
            bufa[np][1] = r1[lane]; bufb[np][1] = r1[64 + lane];
        }
        #pragma unroll
        for (int rr = 0; rr < 2; ++rr) {
            const float4 xa = bufa[cp][rr];
            const float4 xb = bufb[cp][rr];
            float acc0 = xa.x * w0a.x + xa.y * w0a.y + xa.z * w0a.z + xa.w * w0a.w
                       + xb.x * w0b.x + xb.y * w0b.y + xb.z * w0b.z + xb.w * w0b.w;
            float acc1 = xa.x * w1a.x + xa.y * w1a.y + xa.z * w1a.z + xa.w * w1a.w
                       + xb.x * w1b.x + xb.y * w1b.y + xb.z * w1b.z + xb.w * w1b.w;
            float acc2 = xa.x * w2a.x + xa.y * w2a.y + xa.z * w2a.z + xa.w * w2a.w
                       + xb.x * w2b.x + xb.y * w2b.y + xb.z * w2b.z + xb.w * w2b.w;
            float acc3 = xa.x * w3a.x + xa.y * w3a.y + xa.z * w3a.z + xa.w * w3a.w
                       + xb.x * w3b.x + xb.y * w3b.y + xb.z * w3b.z + xb.w * w3b.w;

            // fold 4 accs -> 1 per lane with quad-local DPP (pure VALU)
            const bool b0 = (lane & 1);
            float pA = b0 ? acc1 : acc0;
            float qA = b0 ? acc0 : acc1;
            pA += dpp_xor1(qA);
            float pB = b0 ? acc3 : acc2;
            float qB = b0 ? acc2 : acc3;
            pB += dpp_xor1(qB);
            const bool b1 = (lane & 2);
            float pv = b1 ? pB : pA;
            float qv = b1 ? pA : pB;
            pv += dpp_xor2(qv);
            // lane holds partial for wire (lane&3), segment (lane>>2)

            part[(wave * A_ROWS_PER_WAVE + 2 * p + rr) * PART_STRIDE + partOff] = pv;
        }
    }
    __syncthreads();

    // ---- tail: one thread per (row, wire), sum 16 segment partials ----
    {
        const int row  = tid >> 2;          // 0..63
        const int wire = tid & 3;
        const float4* seg4 = (const float4*)&part[row * PART_STRIDE + wire * 16];
        const float4 s0 = seg4[0], s1 = seg4[1], s2 = seg4[2], s3 = seg4[3];
        const float s = ((s0.x + s0.y) + (s0.z + s0.w))
                      + ((s1.x + s1.y) + (s1.z + s1.w))
                      + ((s2.x + s2.y) + (s2.z + s2.w))
                      + ((s3.x + s3.y) + (s3.z + s3.w));
        const float z = s + b_pre[wire];
        // tanh(z) = 1 - 2/(exp(2z)+1), exp via hardware v_exp_f32
        const float e = __expf(2.f * z);
        const float th = 1.f - 2.f / (e + 1.f);
        angles[(size_t)blockIdx.x * A_ROWS_PER_BLOCK * NQ + tid] =
            th * 3.14159265358979323846f;
    }
}

// ============ Kernel B: quantum sim + post-net, one thread per row ============
#define B_BLOCK 256

__global__ __launch_bounds__(B_BLOCK, 4) void vqc_kernel(
    const float* __restrict__ angles,
    const float* __restrict__ q_weights,
    const float* __restrict__ W_post,
    const float* __restrict__ b_post,
    float* __restrict__ out)
{
    __shared__ float gates[NL * NQ][8];
    __shared__ float Wpost_s[NC * NQ];
    __shared__ float bpost_s[NC];

    const int tid = threadIdx.x;

    // precompute the 24 Rot gate matrices (batch-invariant)
    if (tid < NL * NQ) {
        const int l = tid >> 2, w = tid & 3;
        const float phi = q_weights[l * 12 + w * 3 + 0];
        const float th  = q_weights[l * 12 + w * 3 + 1];
        const float om  = q_weights[l * 12 + w * 3 + 2];
        const float c  = cosf(0.5f * th), s = sinf(0.5f * th);
        const float hp = 0.5f * (phi + om), hm = 0.5f * (phi - om);
        const float epr = cosf(hp), epi = -sinf(hp);   // exp(-i(phi+om)/2)
        const float emr = cosf(hm), emi = -sinf(hm);   // exp(-i(phi-om)/2)
        gates[tid][0] =  epr * c;  gates[tid][1] =  epi * c;   // g00 = ep*c
        gates[tid][2] = -emr * s;  gates[tid][3] =  emi * s;   // g01 = -conj(em)*s
        gates[tid][4] =  emr * s;  gates[tid][5] =  emi * s;   // g10 = em*s
        gates[tid][6] =  epr * c;  gates[tid][7] = -epi * c;   // g11 = conj(ep)*c
    }
    if (tid >= 64 && tid < 64 + NC * NQ) Wpost_s[tid - 64] = W_post[tid - 64];
    if (tid >= 104 && tid < 104 + NC)    bpost_s[tid - 104] = b_post[tid - 104];
    __syncthreads();

    const int r = blockIdx.x * B_BLOCK + tid;
    const float4 a = ((const float4*)angles)[r];   // coalesced 16B/lane

    float c0, s0, c1, s1, c2, s2, c3, s3;
    __sincosf(0.5f * a.x, &s0, &c0);
    __sincosf(0.5f * a.y, &s1, &c1);
    __sincosf(0.5f * a.z, &s2, &c2);
    __sincosf(0.5f * a.w, &s3, &c3);

    // |psi> = RY(a0)|0> x RY(a1)|0> x RY(a2)|0> x RY(a3)|0>  (real)
    float ar[16], ai[16];
    #pragma unroll
    for (int i = 0; i < 16; ++i) {
        ar[i] = ((i & 8) ? s0 : c0) * ((i & 4) ? s1 : c1)
              * ((i & 2) ? s2 : c2) * ((i & 1) ? s3 : c3);
        ai[i] = 0.f;
    }

    #pragma unroll
    for (int l = 0; l < NL; ++l) {
        #pragma unroll
        for (int w = 0; w < NQ; ++w) {
            const float* G = gates[l * 4 + w];     // LDS broadcast, conflict-free
            const float g00r = G[0], g00i = G[1], g01r = G[2], g01i = G[3];
            const float g10r = G[4], g10i = G[5], g11r = G[6], g11i = G[7];
            const int m = 8 >> w;
            #pragma unroll
            for (int i0 = 0; i0 < 16; ++i0) {
                if (i0 & m) continue;
                const int i1 = i0 | m;
                const float A0r = ar[i0], A0i = ai[i0];
                const float A1r = ar[i1], A1i = ai[i1];
                ar[i0] = g00r * A0r - g00i * A0i + g01r * A1r - g01i * A1i;
                ai[i0] = g00r * A0i + g00i * A0r + g01r * A1i + g01i * A1r;
                ar[i1] = g10r * A0r - g10i * A0i + g11r * A1r - g11i * A1i;
                ai[i1] = g10r * A0i + g10i * A0r + g11r * A1i + g11i * A1r;
            }
        }
        const int rshift = l % 3 + 1;
        // CNOT ring: pure compile-time register permutation
        #pragma unroll
        for (int w = 0; w < NQ; ++w) {
            const int cm = 8 >> w;
            const int tm = 8 >> ((w + rshift) & 3);
            #pragma unroll
            for (int i = 0; i < 16; ++i) {
                if ((i & cm) && !(i & tm)) {
                    const int ii = i | tm;
                    float t;
                    t = ar[i]; ar[i] = ar[ii]; ar[ii] = t;
                    t = ai[i]; ai[i] = ai[ii]; ai[ii] = t;
                }
            }
        }
    }

    // Z expectations per wire
    float e0 = 0.f, e1 = 0.f, e2 = 0.f, e3 = 0.f;
    #pragma unroll
    for (int i = 0; i < 16; ++i) {
        const float pr = ar[i] * ar[i] + ai[i] * ai[i];
        e0 += (i & 8) ? -pr : pr;
        e1 += (i & 4) ? -pr : pr;
        e2 += (i & 2) ? -pr : pr;
        e3 += (i & 1) ? -pr : pr;
    }

    // post-net 4 -> 10, stored as 5 aligned float2 (row byte offset 40r, 8B-aligned)
    float o[NC];
    #pragma unroll
    for (int c = 0; c < NC; ++c) {
        o[c] = bpost_s[c]
             + Wpost_s[c * 4 + 0] * e0 + Wpost_s[c * 4 + 1] * e1
             + Wpost_s[c * 4 + 2] * e2 + Wpost_s[c * 4 + 3] * e3;
    }
    float2* orow2 = (float2*)(out + (size_t)r * NC);
    #pragma unroll
    for (int c = 0; c < 5; ++c)
        orow2[c] = make_float2(o[2 * c], o[2 * c + 1]);
}

extern "C" void kernel_launch(void* const* d_in, const int* in_sizes, int n_in,
                              void* d_out, int out_size, void* d_ws, size_t ws_size,
                              hipStream_t stream) {
    const float* x         = (const float*)d_in[0];
    const float* W_pre     = (const float*)d_in[1];
    const float* b_pre     = (const float*)d_in[2];
    const float* q_weights = (const float*)d_in[3];
    const float* W_post    = (const float*)d_in[4];
    const float* b_post    = (const float*)d_in[5];
    float* out    = (float*)d_out;
    float* angles = (float*)d_ws;               // 65536*4 floats = 1 MB

    const int B = in_sizes[0] / K;              // 65536
    dim3 gridA(B / A_ROWS_PER_BLOCK);           // 1024 blocks -> 4/CU, 1 round
    prenet_kernel<<<gridA, A_BLOCK, 0, stream>>>(x, W_pre, b_pre, angles);
    dim3 gridB(B / B_BLOCK);                    // 256 blocks
    vqc_kernel<<<gridB, B_BLOCK, 0, stream>>>(angles, q_weights, W_post, b_post, out);
}